// Round 6
// baseline (129.480 us; speedup 1.0000x reference)
//
#include <hip/hip_runtime.h>

#define VOCAB 50000
#define EMBED 256
#define NB    16
#define NC    64
#define NS    512
#define UNK   1

// ---- bf16 fast path (R13): R12 + 2-j unroll for 2x outstanding gathers ----
// R12 (128.5 us, best): reg q-rows + 2048-block grid beat the 131 baseline.
// Scores still ~27 us moving 268 MB at ~9.6 TB/s effective with nothing
// saturated -> raise per-wave memory-level parallelism. R13 issues 16 row
// gathers per unrolled step (two j's) before consuming either. VGPR ~80-90
// (qr 16 + ga/gb 32 + acc 8) -> 5-6 waves/SIMD; net outstanding loads/CU
// ~1.5x R12. No __launch_bounds__ min-wave cap (R8/R9 spill trap).
// Spill sentinel: scores WRITE_SIZE must stay ~0.1 MB.
#define CTILE 8               // c's per block
#define JT    16              // j tiles
#define JLEN  (NS / JT)       // 32 j's per tile
#define BF_TABLE_BYTES ((size_t)VOCAB * EMBED * 2)          // 25,600,000
#define PARTIAL_ELEMS  (JT * NB * NC)                       // 16384

__device__ __forceinline__ unsigned short f2bf_rne(float f) {
    unsigned int u = __float_as_uint(f);
    u = (u + 0x7fffu + ((u >> 16) & 1u)) >> 16;             // round-nearest-even
    return (unsigned short)u;
}

// Stream-convert emb f32 -> bf16 table in ws. 400k threads x 8 elems.
__global__ __launch_bounds__(256) void convert_kernel(
    const float* __restrict__ emb, unsigned int* __restrict__ bf)
{
    const size_t t = (size_t)blockIdx.x * 256 + threadIdx.x;
    const float4* __restrict__ e4 = (const float4*)emb;
    const float4 a = e4[t * 2];
    const float4 b = e4[t * 2 + 1];
    uint4 r;
    r.x = (unsigned int)f2bf_rne(a.x) | ((unsigned int)f2bf_rne(a.y) << 16);
    r.y = (unsigned int)f2bf_rne(a.z) | ((unsigned int)f2bf_rne(a.w) << 16);
    r.z = (unsigned int)f2bf_rne(b.x) | ((unsigned int)f2bf_rne(b.y) << 16);
    r.w = (unsigned int)f2bf_rne(b.z) | ((unsigned int)f2bf_rne(b.w) << 16);
    ((uint4*)bf)[t] = r;
}

// Gather-bound scores. Grid = NB * (NC/CTILE) * JT = 2048 blocks, 256 thr.
// Wave w owns j = w, w+4, ... (8 j's); q rows preloaded into 16 VGPRs
// (zero-padded past nnz). Per unrolled step: 16 full-row uint2 gathers
// (one 512-B row per instruction, fully coalesced), then both FMA blocks.
__global__ __launch_bounds__(256) void scores_bf_kernel(
    const int* __restrict__ src, const int* __restrict__ q,
    const unsigned int* __restrict__ bf, float* __restrict__ partial)
{
    const int x  = blockIdx.x;
    const int jt = x & (JT - 1);
    const int ct = (x >> 4) & (NC / CTILE - 1);
    const int b  = x >> 7;
    const int c0 = ct * CTILE;
    const int j0 = jt * JLEN;

    const int tid  = threadIdx.x;
    const int wave = tid >> 6;
    const int lane = tid & 63;          // covers row bytes [8*lane, 8*lane+8)

    const uint2* __restrict__ bfe = (const uint2*)bf;       // 64 uint2 per row
    const int* __restrict__ qrow = q + (size_t)b * NS;
    const int* __restrict__ srow = src + ((size_t)b * NC + c0) * NS;

    __shared__ int sids[CTILE][JLEN];   // 1 KB clamped source ids
    __shared__ int qids[JLEN];
    __shared__ int nnz_sh;

    if (tid < 64) {                                  // wave 0
        const int qv = (tid < JLEN) ? qrow[j0 + tid] : 0;
        if (tid < JLEN) qids[tid] = (qv >= VOCAB) ? UNK : qv;
        const unsigned long long bal = __ballot(qv > 0);
        if (tid == 0) nnz_sh = __popcll(bal);        // contiguous prefix in tile
    }
    {   // 256 tile ids, 1 per thread, coalesced
        const int i  = tid >> 5;        // c within tile (0..7)
        const int j  = tid & (JLEN - 1);
        const int sv = srow[(size_t)i * NS + j0 + j];
        sids[i][j] = (sv >= VOCAB) ? UNK : sv;
    }
    __syncthreads();

    const int nnz = nnz_sh;

    // preload this wave's q rows (bf16) into registers: j = wave + 4*it.
    // Zero-padded past nnz so trailing FMAs contribute exactly 0.
    // Static indexing only (rule: runtime-indexed arrays spill to scratch).
    uint2 qr[8];
#pragma unroll
    for (int it = 0; it < 8; ++it) {
        const int j = wave + it * 4;
        qr[it] = (j < nnz) ? bfe[(size_t)qids[j] * 64 + lane]
                           : make_uint2(0u, 0u);
    }

    float acc[CTILE];
#pragma unroll
    for (int i = 0; i < CTILE; i++) acc[i] = 0.f;

#pragma unroll
    for (int ip = 0; ip < 4; ++ip) {
        const int ja = wave + (ip * 2) * 4;
        const int jb = wave + (ip * 2 + 1) * 4;
        if (ja >= nnz) break;           // nnz block-uniform, ja wave-uniform
        // jb may be past nnz: gather ja's rows instead (valid address; the
        // zeroed qr[2ip+1] kills the contribution; avoids NaN*0 from junk).
        const int jbs = (jb < nnz) ? jb : ja;

        uint2 ga[CTILE], gb[CTILE];     // 16 gathers in flight
#pragma unroll
        for (int i = 0; i < CTILE; i++)
            ga[i] = bfe[(size_t)sids[i][ja] * 64 + lane];   // 512-B row/instr
#pragma unroll
        for (int i = 0; i < CTILE; i++)
            gb[i] = bfe[(size_t)sids[i][jbs] * 64 + lane];

        const float qa0 = __uint_as_float(qr[ip * 2].x << 16);
        const float qa1 = __uint_as_float(qr[ip * 2].x & 0xffff0000u);
        const float qa2 = __uint_as_float(qr[ip * 2].y << 16);
        const float qa3 = __uint_as_float(qr[ip * 2].y & 0xffff0000u);
        const float qb0 = __uint_as_float(qr[ip * 2 + 1].x << 16);
        const float qb1 = __uint_as_float(qr[ip * 2 + 1].x & 0xffff0000u);
        const float qb2 = __uint_as_float(qr[ip * 2 + 1].y << 16);
        const float qb3 = __uint_as_float(qr[ip * 2 + 1].y & 0xffff0000u);

#pragma unroll
        for (int i = 0; i < CTILE; i++) {
            const float a0 = __uint_as_float(ga[i].x << 16);
            const float a1 = __uint_as_float(ga[i].x & 0xffff0000u);
            const float a2 = __uint_as_float(ga[i].y << 16);
            const float a3 = __uint_as_float(ga[i].y & 0xffff0000u);
            acc[i] += a0 * qa0 + a1 * qa1 + a2 * qa2 + a3 * qa3;
            const float b0 = __uint_as_float(gb[i].x << 16);
            const float b1 = __uint_as_float(gb[i].x & 0xffff0000u);
            const float b2 = __uint_as_float(gb[i].y << 16);
            const float b3 = __uint_as_float(gb[i].y & 0xffff0000u);
            acc[i] += b0 * qb0 + b1 * qb1 + b2 * qb2 + b3 * qb3;
        }
    }

#pragma unroll
    for (int off = 32; off > 0; off >>= 1)
#pragma unroll
        for (int i = 0; i < CTILE; i++)
            acc[i] += __shfl_down(acc[i], off, 64);

    __shared__ float red[4][CTILE];
    if (lane == 0)
#pragma unroll
        for (int i = 0; i < CTILE; i++) red[wave][i] = acc[i];
    __syncthreads();

    if (tid < CTILE) {
        const float s = red[0][tid] + red[1][tid] + red[2][tid] + red[3][tid];
        partial[(size_t)jt * (NB * NC) + b * NC + c0 + tid] = s;
    }
}

// ---- f32 fallback (proven R5 path), JT=8/JLEN=64, CTILE=8 ----
__global__ __launch_bounds__(256) void scores_f32_kernel(
    const int* __restrict__ src, const int* __restrict__ q,
    const float* __restrict__ emb, float* __restrict__ partial)
{
    const int x  = blockIdx.x;
    const int jt = x & 7;
    const int ct = (x >> 3) & 7;
    const int b  = x >> 6;
    const int c0 = ct * 8;
    const int j0 = jt * 64;

    const int tid = threadIdx.x, wave = tid >> 6, lane = tid & 63;
    const float4* __restrict__ emb4 = (const float4*)emb;
    const int* __restrict__ qrow = q + (size_t)b * NS;
    const int* __restrict__ srow = src + ((size_t)b * NC + c0) * NS;

    float acc[8];
#pragma unroll
    for (int i = 0; i < 8; i++) acc[i] = 0.f;

    for (int j = j0 + wave; j < j0 + 64; j += 4) {
        const int qv = qrow[j];
        if (qv > 0) {
            const int qid = (qv >= VOCAB) ? UNK : qv;
            const float4 eq = emb4[(size_t)qid * (EMBED / 4) + lane];
            float4 a[8];
#pragma unroll
            for (int i = 0; i < 8; i++) {
                const int sv = srow[(size_t)i * NS + j];
                a[i] = emb4[(size_t)((sv >= VOCAB) ? UNK : sv) * (EMBED / 4) + lane];
            }
#pragma unroll
            for (int i = 0; i < 8; i++)
                acc[i] += a[i].x * eq.x + a[i].y * eq.y + a[i].z * eq.z + a[i].w * eq.w;
        }
    }
#pragma unroll
    for (int off = 32; off > 0; off >>= 1)
#pragma unroll
        for (int i = 0; i < 8; i++)
            acc[i] += __shfl_down(acc[i], off, 64);

    __shared__ float red[4][8];
    if (lane == 0)
#pragma unroll
        for (int i = 0; i < 8; i++) red[wave][i] = acc[i];
    __syncthreads();
    if (tid < 8)
        partial[(size_t)jt * (NB * NC) + b * NC + c0 + tid] =
            red[0][tid] + red[1][tid] + red[2][tid] + red[3][tid];
}

// One block per b. Wave 0: sum jtn partials -> softmax -> sims + argmax;
// then all 256 threads copy the winning source row as f32.
__global__ __launch_bounds__(256) void finalize_kernel(
    const float* __restrict__ partial, const int* __restrict__ src,
    float* __restrict__ out, int jtn)
{
    const int b = blockIdx.x, tid = threadIdx.x;
    __shared__ int top_sh;

    if (tid < 64) {
        float s = 0.f;
        for (int t = 0; t < jtn; t++)
            s += partial[(size_t)t * (NB * NC) + b * NC + tid];

        float m = s;
#pragma unroll
        for (int off = 32; off > 0; off >>= 1)
            m = fmaxf(m, __shfl_xor(m, off, 64));
        const float e = expf(s - m);
        float sum = e;
#pragma unroll
        for (int off = 32; off > 0; off >>= 1)
            sum += __shfl_xor(sum, off, 64);

        out[NB * NS + b * NC + tid] = e / sum;       // sims after 8192 ids

        const unsigned long long ballot = __ballot(s == m);
        if (tid == 0) top_sh = __ffsll(ballot) - 1;  // first occurrence
    }
    __syncthreads();

    const int top = top_sh;
    const int* __restrict__ srow = src + ((size_t)b * NC + top) * NS;
    for (int j = tid; j < NS; j += 256)
        out[b * NS + j] = (float)srow[j];
}

extern "C" void kernel_launch(void* const* d_in, const int* in_sizes, int n_in,
                              void* d_out, int out_size, void* d_ws, size_t ws_size,
                              hipStream_t stream) {
    const int*   src = (const int*)d_in[0];    // [NB*NC, NS] int32
    const int*   q   = (const int*)d_in[1];    // [NB, NS] int32
    const float* emb = (const float*)d_in[3];  // [VOCAB, EMBED] f32
    float* out = (float*)d_out;                // 8192 out_sources + 1024 sims (f32)

    if (ws_size >= BF_TABLE_BYTES + PARTIAL_ELEMS * sizeof(float)) {
        unsigned int* bf = (unsigned int*)d_ws;
        float* partial = (float*)((char*)d_ws + BF_TABLE_BYTES);
        convert_kernel<<<VOCAB * EMBED / 2048, 256, 0, stream>>>(emb, bf);
        scores_bf_kernel<<<NB * (NC / CTILE) * JT, 256, 0, stream>>>(src, q, bf, partial);
        finalize_kernel<<<NB, 256, 0, stream>>>(partial, src, out, JT);
    } else {
        float* partial = (float*)d_ws;         // 8192 floats
        scores_f32_kernel<<<NB * 8 * 8, 256, 0, stream>>>(src, q, emb, partial);
        finalize_kernel<<<NB, 256, 0, stream>>>(partial, src, out, 8);
    }
}